// Round 5
// baseline (37315.649 us; speedup 1.0000x reference)
//
#include <hip/hip_runtime.h>
#include <math.h>

typedef float v2f __attribute__((ext_vector_type(2)));

#define TT 1024

__device__ __forceinline__ float fast_tanh(float v) {
    float e = __expf(2.f * v);      // v>>0: e=inf -> 1; v<<0: e=0 -> -1 (NaN-free)
    return 1.f - 2.f / (e + 1.f);
}
__device__ __forceinline__ float fast_sig(float v) {
    return 1.f / (1.f + __expf(-v));
}

template <int CTRL>
__device__ __forceinline__ float dpp_add(float v) {
    int m = __builtin_amdgcn_update_dpp(0, __float_as_int(v), CTRL, 0xF, 0xF, true);
    return v + __int_as_float(m);
}
// Full sum over each aligned 8-lane group (all lanes get the sum):
// xor1 (quad_perm[1,0,3,2]=0xB1), xor2 (quad_perm[2,3,0,1]=0x4E),
// then row_half_mirror (0x141) adds the other quad of the 8-group.
__device__ __forceinline__ float red8(float v) {
    v = dpp_add<0xB1>(v);
    v = dpp_add<0x4E>(v);
    v = dpp_add<0x141>(v);
    return v;
}

// 256 blocks x 512 threads; block owns batches {2b, 2b+1}; 1 block/CU.
// Long-col dot (t<480): col-set 8cg..8cg+7 (cg=t>>3) over u-slice [16ue,16ue+16)
//   (ue=t&7). h1 stored batch-interleaved+padded in LDS; one b128 read yields
//   two (b0,b1) float2 pairs -> packed FMA. After the dot, red8() completes
//   each column's inner product across the 8-lane group (VALU DPP, no LDS);
//   lane ue selects col 8cg+ue (== t) and writes ONE b32 per batch.
// rk2 dot (t in [480,504)): 4 cols x full 32 u, no reduction needed.
// Update: t<256 GRU1 unit (h_old in reg); t in [256,320) GRU2 lag-1 unit.
// NOTE: the dot phase runs at EVERY iteration incl. the drain step i==TT —
// GRU2's final update needs k2·h1(TT-1) / rk2·h2(TT-2) computed there.
__global__ __launch_bounds__(512, 1)
void gru_stack_kernel(const float* __restrict__ x,   // [512,1024,1]
                      const float* __restrict__ k1,  // [1,384]
                      const float* __restrict__ rk1, // [128,384]
                      const float* __restrict__ b1,  // [2,384]
                      const float* __restrict__ k2,  // [128,96]
                      const float* __restrict__ rk2, // [32,96]
                      const float* __restrict__ b2,  // [2,96]
                      const float* __restrict__ wd,  // [32,1]
                      const float* __restrict__ bd,  // [1]
                      float* __restrict__ out)       // [512,1]
{
    // h1 interleaved: slice s (u=16s..16s+15): h1i[44*s + 2*j + b], pad 44
    // (44*4=176 B is 16B-aligned; 44*ue mod 32 spans 8 distinct bank-quads).
    __shared__ __align__(16) float h1i[8 * 44];
    __shared__ __align__(16) float h2i[64];           // h2i[2*j + b]
    __shared__ __align__(16) float part1[2][480];     // complete inners: rk1|k2 cols
    __shared__ __align__(16) float part2[2][96];      // complete rk2 inners

    const int t  = threadIdx.x;
    const int b0 = blockIdx.x * 2;

    if (t < 8 * 44) h1i[t] = 0.f;
    if (t >= 448 && t < 512) h2i[t - 448] = 0.f;

    // ---------------- dot-role setup ----------------
    const int ue = t & 7, cg = t >> 3;
    float w_[8][16];                 // long cols: 8 cols x 16 u  (128 VGPRs)
    float w2_[4][32];                // rk2: 4 cols x 32 u        (128 VGPRs)
    if (t < 480) {
#pragma unroll
        for (int r = 0; r < 8; ++r) {
            const int c = 8 * cg + r;
#pragma unroll
            for (int j = 0; j < 16; ++j) {
                const int u = 16 * ue + j;
                w_[r][j] = (c < 384) ? rk1[u * 384 + c] : k2[u * 96 + (c - 384)];
            }
        }
    } else if (t < 504) {
        const int c4 = 4 * (t - 480);
#pragma unroll
        for (int r = 0; r < 4; ++r)
#pragma unroll
            for (int u = 0; u < 32; ++u) w2_[r][u] = rk2[u * 96 + c4 + r];
    }
    const bool ue1 = ue & 1, ue2 = ue & 2, ue4 = ue & 4;

    // ---------------- update-role setup ----------------
    const int ju = t & 127, bu = t >> 7;               // t<256: GRU1 update
    float k1z = 0, k1r = 0, k1h = 0, bz = 0, br = 0, bhx = 0, bhr = 0, h_old = 0;
    if (t < 256) {
        k1z = k1[ju]; k1r = k1[128 + ju]; k1h = k1[256 + ju];
        bz  = b1[ju]       + b1[384 + ju];
        br  = b1[128 + ju] + b1[384 + 128 + ju];
        bhx = b1[256 + ju];
        bhr = b1[384 + 256 + ju];
    }
    const int tau = t - 256, j2 = tau & 31, bb2 = tau >> 5;  // [256,320): GRU2 update
    float bz2 = 0, br2 = 0, bh2x = 0, bh2r = 0, h2_old = 0;
    if (t >= 256 && t < 320) {
        bz2  = b2[j2]      + b2[96 + j2];
        br2  = b2[32 + j2] + b2[96 + 32 + j2];
        bh2x = b2[64 + j2];
        bh2r = b2[96 + 64 + j2];
    }

    __syncthreads();  // B0: h init visible

    for (int i = 0; i <= TT; ++i) {
        float xv = 0.f;
        if (t < 256 && i < TT) xv = x[(b0 + bu) * TT + i];

        // Dot phase: runs every iteration INCLUDING i==TT (pipeline drain).
        if (t < 480) {
            const float4* pb = (const float4*)&h1i[44 * ue];
            v2f acc[8];
#pragma unroll
            for (int r = 0; r < 8; ++r) acc[r] = (v2f){0.f, 0.f};
#pragma unroll
            for (int q = 0; q < 8; ++q) {          // 8 float4 = 16 u-pairs
                float4 hv = pb[q];
                v2f p0 = {hv.x, hv.y};             // (b0,b1) at u=16ue+2q
                v2f p1 = {hv.z, hv.w};             // u=16ue+2q+1
#pragma unroll
                for (int r = 0; r < 8; ++r) {
                    acc[r] += p0 * w_[r][2 * q];
                    acc[r] += p1 * w_[r][2 * q + 1];
                }
            }
            float f0[8], f1[8];
#pragma unroll
            for (int r = 0; r < 8; ++r) {
                f0[r] = red8(acc[r].x);
                f1[r] = red8(acc[r].y);
            }
            // lane ue picks column 8cg+ue == t (3-level cndmask tree)
            float x0 = ue1 ? f0[1] : f0[0], x1 = ue1 ? f0[3] : f0[2];
            float x2 = ue1 ? f0[5] : f0[4], x3 = ue1 ? f0[7] : f0[6];
            float y0 = ue2 ? x1 : x0, y1 = ue2 ? x3 : x2;
            part1[0][t] = ue4 ? y1 : y0;
            float z0 = ue1 ? f1[1] : f1[0], z1 = ue1 ? f1[3] : f1[2];
            float z2 = ue1 ? f1[5] : f1[4], z3 = ue1 ? f1[7] : f1[6];
            float q0 = ue2 ? z1 : z0, q1 = ue2 ? z3 : z2;
            part1[1][t] = ue4 ? q1 : q0;
        } else if (t < 504) {
            const int c4 = 4 * (t - 480);
            const float4* pb2 = (const float4*)h2i;
            v2f acc[4];
#pragma unroll
            for (int r = 0; r < 4; ++r) acc[r] = (v2f){0.f, 0.f};
#pragma unroll
            for (int q = 0; q < 16; ++q) {
                float4 hv = pb2[q];
                v2f p0 = {hv.x, hv.y};
                v2f p1 = {hv.z, hv.w};
#pragma unroll
                for (int r = 0; r < 4; ++r) {
                    acc[r] += p0 * w2_[r][2 * q];
                    acc[r] += p1 * w2_[r][2 * q + 1];
                }
            }
#pragma unroll
            for (int r = 0; r < 4; ++r) {
                part2[0][c4 + r] = acc[r].x;
                part2[1][c4 + r] = acc[r].y;
            }
        }
        __syncthreads();  // B1: inners visible

        if (t < 256 && i < TT) {
            // GRU1 unit update: z/r = relu, hh = tanh (reset_after)
            float iz = part1[bu][ju];
            float ir = part1[bu][128 + ju];
            float ih = part1[bu][256 + ju];
            float z  = fmaxf(fmaf(xv, k1z, bz) + iz, 0.f);
            float r  = fmaxf(fmaf(xv, k1r, br) + ir, 0.f);
            float hh = fast_tanh(fmaf(xv, k1h, bhx) + r * (ih + bhr));
            h_old = fmaf(z, h_old - hh, hh);
            h1i[44 * (ju >> 4) + 2 * (ju & 15) + bu] = h_old;
        } else if (t >= 256 && t < 320 && i >= 1) {
            // GRU2 unit update (one step behind): z/r = sigmoid, hh = relu
            float xz = part1[bb2][384 + j2];
            float xr = part1[bb2][384 + 32 + j2];
            float xh = part1[bb2][384 + 64 + j2];
            float iz = part2[bb2][j2];
            float ir = part2[bb2][32 + j2];
            float ih = part2[bb2][64 + j2];
            float z  = fast_sig(xz + iz + bz2);
            float r  = fast_sig(xr + ir + br2);
            float hh = fmaxf(xh + bh2x + r * (ih + bh2r), 0.f);
            h2_old = fmaf(z, h2_old - hh, hh);
            h2i[2 * j2 + bb2] = h2_old;
        }
        __syncthreads();  // B2: h updated
    }

    // ---------------- dense head ----------------
    if (t < 64) {
        const int b = t >> 5, j = t & 31;
        float p = h2i[2 * j + b] * wd[j];
#pragma unroll
        for (int m = 16; m >= 1; m >>= 1) p += __shfl_xor(p, m, 64);
        if (j == 0) out[b0 + b] = p + bd[0];
    }
}

extern "C" void kernel_launch(void* const* d_in, const int* in_sizes, int n_in,
                              void* d_out, int out_size, void* d_ws, size_t ws_size,
                              hipStream_t stream) {
    const float* x   = (const float*)d_in[0];
    const float* k1  = (const float*)d_in[1];
    const float* rk1 = (const float*)d_in[2];
    const float* b1  = (const float*)d_in[3];
    const float* k2  = (const float*)d_in[4];
    const float* rk2 = (const float*)d_in[5];
    const float* b2  = (const float*)d_in[6];
    const float* wd  = (const float*)d_in[7];
    const float* bd  = (const float*)d_in[8];
    float* out = (float*)d_out;

    dim3 grid(256), block(512);
    hipLaunchKernelGGL(gru_stack_kernel, grid, block, 0, stream,
                       x, k1, rk1, b1, k2, rk2, b2, wd, bd, out);
}

// Round 6
// 6295.749 us; speedup vs baseline: 5.9271x; 5.9271x over previous
//
#include <hip/hip_runtime.h>
#include <math.h>

typedef float v2f __attribute__((ext_vector_type(2)));

#define TT 1024

__device__ __forceinline__ float fast_tanh(float v) {
    float e = __expf(2.f * v);      // v>>0: e=inf -> 1; v<<0: e=0 -> -1 (NaN-free)
    return 1.f - 2.f / (e + 1.f);
}
__device__ __forceinline__ float fast_sig(float v) {
    return 1.f / (1.f + __expf(-v));
}

template <int CTRL>
__device__ __forceinline__ float dpp_add(float v) {
    int m = __builtin_amdgcn_update_dpp(0, __float_as_int(v), CTRL, 0xF, 0xF, true);
    return v + __int_as_float(m);
}
// Full sum over each aligned 8-lane group (all lanes get the sum):
// xor1 (quad_perm[1,0,3,2]=0xB1), xor2 (quad_perm[2,3,0,1]=0x4E),
// then row_half_mirror (0x141) adds the other quad of the 8-group.
__device__ __forceinline__ float red8(float v) {
    v = dpp_add<0xB1>(v);
    v = dpp_add<0x4E>(v);
    v = dpp_add<0x141>(v);
    return v;
}

// 256 blocks x 512 threads; block owns batches {2b, 2b+1}; 1 block/CU.
// Long-col dot (t<480): col-set 8cg..8cg+7 (cg=t>>3) over u-slice [16ue,16ue+16)
//   (ue=t&7). h1 batch-interleaved+padded in LDS; one b128 read -> two (b0,b1)
//   float2 pairs -> packed FMA. red8() completes each column's inner product
//   across the 8-lane group (VALU DPP, no LDS); lane ue keeps col 8cg+ue == t.
// rk2 dot (t in [480,504)): 4 cols x full 32 u, no reduction needed.
// IMPORTANT: both roles share ONE flat 128-float register array (wreg) —
//   wave 7 spans both roles; two separate arrays double live registers and
//   spill to scratch (R5: 45 GB FETCH). Long role: wreg[r*16+j]; rk2: wreg[r*32+u].
// Update: t<256 GRU1 unit (h_old in reg); t in [256,320) GRU2 lag-1 unit.
// Dot phase runs at EVERY iteration incl. drain i==TT (GRU2's last update
// needs k2·h1(TT-1) / rk2·h2(TT-2) computed there).
__global__ __launch_bounds__(512, 1)
void gru_stack_kernel(const float* __restrict__ x,   // [512,1024,1]
                      const float* __restrict__ k1,  // [1,384]
                      const float* __restrict__ rk1, // [128,384]
                      const float* __restrict__ b1,  // [2,384]
                      const float* __restrict__ k2,  // [128,96]
                      const float* __restrict__ rk2, // [32,96]
                      const float* __restrict__ b2,  // [2,96]
                      const float* __restrict__ wd,  // [32,1]
                      const float* __restrict__ bd,  // [1]
                      float* __restrict__ out)       // [512,1]
{
    // h1 interleaved: slice s (u=16s..16s+15): h1i[44*s + 2*j + b], pad 44.
    __shared__ __align__(16) float h1i[8 * 44];
    __shared__ __align__(16) float h2i[64];           // h2i[2*j + b]
    __shared__ __align__(16) float part1[2][480];     // complete inners: rk1|k2 cols
    __shared__ __align__(16) float part2[2][96];      // complete rk2 inners

    const int t  = threadIdx.x;
    const int b0 = blockIdx.x * 2;

    if (t < 8 * 44) h1i[t] = 0.f;
    if (t >= 448 && t < 512) h2i[t - 448] = 0.f;

    // ---------------- dot-role setup (single shared register array) ----------
    const int ue = t & 7, cg = t >> 3;
    float wreg[128];
    if (t < 480) {
#pragma unroll
        for (int r = 0; r < 8; ++r) {
            const int c = 8 * cg + r;
#pragma unroll
            for (int j = 0; j < 16; ++j) {
                const int u = 16 * ue + j;
                wreg[r * 16 + j] = (c < 384) ? rk1[u * 384 + c]
                                             : k2[u * 96 + (c - 384)];
            }
        }
    } else if (t < 504) {
        const int c4 = 4 * (t - 480);
#pragma unroll
        for (int r = 0; r < 4; ++r)
#pragma unroll
            for (int u = 0; u < 32; ++u) wreg[r * 32 + u] = rk2[u * 96 + c4 + r];
    } else {
#pragma unroll
        for (int j = 0; j < 128; ++j) wreg[j] = 0.f;
    }
    const bool ue1 = ue & 1, ue2 = ue & 2, ue4 = ue & 4;

    // ---------------- update-role setup ----------------
    const int ju = t & 127, bu = t >> 7;               // t<256: GRU1 update
    float k1z = 0, k1r = 0, k1h = 0, bz = 0, br = 0, bhx = 0, bhr = 0, h_old = 0;
    if (t < 256) {
        k1z = k1[ju]; k1r = k1[128 + ju]; k1h = k1[256 + ju];
        bz  = b1[ju]       + b1[384 + ju];
        br  = b1[128 + ju] + b1[384 + 128 + ju];
        bhx = b1[256 + ju];
        bhr = b1[384 + 256 + ju];
    }
    const int tau = t - 256, j2 = tau & 31, bb2 = tau >> 5;  // [256,320): GRU2 update
    float bz2 = 0, br2 = 0, bh2x = 0, bh2r = 0, h2_old = 0;
    if (t >= 256 && t < 320) {
        bz2  = b2[j2]      + b2[96 + j2];
        br2  = b2[32 + j2] + b2[96 + 32 + j2];
        bh2x = b2[64 + j2];
        bh2r = b2[96 + 64 + j2];
    }

    __syncthreads();  // B0: h init visible

    for (int i = 0; i <= TT; ++i) {
        float xv = 0.f;
        if (t < 256 && i < TT) xv = x[(b0 + bu) * TT + i];

        // Dot phase: runs every iteration INCLUDING i==TT (pipeline drain).
        if (t < 480) {
            const float4* pb = (const float4*)&h1i[44 * ue];
            v2f acc[8];
#pragma unroll
            for (int r = 0; r < 8; ++r) acc[r] = (v2f){0.f, 0.f};
#pragma unroll
            for (int q = 0; q < 8; ++q) {          // 8 float4 = 16 u-pairs
                float4 hv = pb[q];
                v2f p0 = {hv.x, hv.y};             // (b0,b1) at u=16ue+2q
                v2f p1 = {hv.z, hv.w};             // u=16ue+2q+1
#pragma unroll
                for (int r = 0; r < 8; ++r) {
                    acc[r] += p0 * wreg[r * 16 + 2 * q];
                    acc[r] += p1 * wreg[r * 16 + 2 * q + 1];
                }
            }
            float f0[8], f1[8];
#pragma unroll
            for (int r = 0; r < 8; ++r) {
                f0[r] = red8(acc[r].x);
                f1[r] = red8(acc[r].y);
            }
            // lane ue picks column 8cg+ue == t (3-level cndmask tree)
            float x0 = ue1 ? f0[1] : f0[0], x1 = ue1 ? f0[3] : f0[2];
            float x2 = ue1 ? f0[5] : f0[4], x3 = ue1 ? f0[7] : f0[6];
            float y0 = ue2 ? x1 : x0, y1 = ue2 ? x3 : x2;
            part1[0][t] = ue4 ? y1 : y0;
            float z0 = ue1 ? f1[1] : f1[0], z1 = ue1 ? f1[3] : f1[2];
            float z2 = ue1 ? f1[5] : f1[4], z3 = ue1 ? f1[7] : f1[6];
            float q0 = ue2 ? z1 : z0, q1 = ue2 ? z3 : z2;
            part1[1][t] = ue4 ? q1 : q0;
        } else if (t < 504) {
            const int c4 = 4 * (t - 480);
            const float4* pb2 = (const float4*)h2i;
            v2f acc[4];
#pragma unroll
            for (int r = 0; r < 4; ++r) acc[r] = (v2f){0.f, 0.f};
#pragma unroll
            for (int q = 0; q < 16; ++q) {
                float4 hv = pb2[q];
                v2f p0 = {hv.x, hv.y};
                v2f p1 = {hv.z, hv.w};
#pragma unroll
                for (int r = 0; r < 4; ++r) {
                    acc[r] += p0 * wreg[r * 32 + 2 * q];
                    acc[r] += p1 * wreg[r * 32 + 2 * q + 1];
                }
            }
#pragma unroll
            for (int r = 0; r < 4; ++r) {
                part2[0][c4 + r] = acc[r].x;
                part2[1][c4 + r] = acc[r].y;
            }
        }
        __syncthreads();  // B1: inners visible

        if (t < 256 && i < TT) {
            // GRU1 unit update: z/r = relu, hh = tanh (reset_after)
            float iz = part1[bu][ju];
            float ir = part1[bu][128 + ju];
            float ih = part1[bu][256 + ju];
            float z  = fmaxf(fmaf(xv, k1z, bz) + iz, 0.f);
            float r  = fmaxf(fmaf(xv, k1r, br) + ir, 0.f);
            float hh = fast_tanh(fmaf(xv, k1h, bhx) + r * (ih + bhr));
            h_old = fmaf(z, h_old - hh, hh);
            h1i[44 * (ju >> 4) + 2 * (ju & 15) + bu] = h_old;
        } else if (t >= 256 && t < 320 && i >= 1) {
            // GRU2 unit update (one step behind): z/r = sigmoid, hh = relu
            float xz = part1[bb2][384 + j2];
            float xr = part1[bb2][384 + 32 + j2];
            float xh = part1[bb2][384 + 64 + j2];
            float iz = part2[bb2][j2];
            float ir = part2[bb2][32 + j2];
            float ih = part2[bb2][64 + j2];
            float z  = fast_sig(xz + iz + bz2);
            float r  = fast_sig(xr + ir + br2);
            float hh = fmaxf(xh + bh2x + r * (ih + bh2r), 0.f);
            h2_old = fmaf(z, h2_old - hh, hh);
            h2i[2 * j2 + bb2] = h2_old;
        }
        __syncthreads();  // B2: h updated
    }

    // ---------------- dense head ----------------
    if (t < 64) {
        const int b = t >> 5, j = t & 31;
        float p = h2i[2 * j + b] * wd[j];
#pragma unroll
        for (int m = 16; m >= 1; m >>= 1) p += __shfl_xor(p, m, 64);
        if (j == 0) out[b0 + b] = p + bd[0];
    }
}

extern "C" void kernel_launch(void* const* d_in, const int* in_sizes, int n_in,
                              void* d_out, int out_size, void* d_ws, size_t ws_size,
                              hipStream_t stream) {
    const float* x   = (const float*)d_in[0];
    const float* k1  = (const float*)d_in[1];
    const float* rk1 = (const float*)d_in[2];
    const float* b1  = (const float*)d_in[3];
    const float* k2  = (const float*)d_in[4];
    const float* rk2 = (const float*)d_in[5];
    const float* b2  = (const float*)d_in[6];
    const float* wd  = (const float*)d_in[7];
    const float* bd  = (const float*)d_in[8];
    float* out = (float*)d_out;

    dim3 grid(256), block(512);
    hipLaunchKernelGGL(gru_stack_kernel, grid, block, 0, stream,
                       x, k1, rk1, b1, k2, rk2, b2, wd, bd, out);
}

// Round 7
// 6279.763 us; speedup vs baseline: 5.9422x; 1.0025x over previous
//
#include <hip/hip_runtime.h>
#include <math.h>

typedef float v2f __attribute__((ext_vector_type(2)));

#define TT 1024

__device__ __forceinline__ float fast_tanh(float v) {
    float e = __expf(2.f * v);      // v>>0: e=inf -> 1; v<<0: e=0 -> -1 (NaN-free)
    return 1.f - 2.f / (e + 1.f);
}
__device__ __forceinline__ float fast_sig(float v) {
    return 1.f / (1.f + __expf(-v));
}

template <int CTRL>
__device__ __forceinline__ float dpp_add(float v) {
    int m = __builtin_amdgcn_update_dpp(0, __float_as_int(v), CTRL, 0xF, 0xF, true);
    return v + __int_as_float(m);
}

// Butterfly reduce-scatter over an aligned 8-lane group.
// Input: a[0..7] = this lane's partial dot for the group's 8 columns.
// Output: the full 8-lane sum of column tau, where tau = (ue&4)? 11-ue : ue
// (s1/s2/s4 are tau's bits). The tau remap makes half-mirror (lane l<->7-l,
// ctrl 0x141) a valid cross-quad combine: tau(7-l)&3 == tau(l)&3.
// Live values shrink 8 -> 4 -> 2 -> 1 (vs 16 live in the all-reduce version),
// which is what keeps arch-VGPR pressure under the spill threshold.
__device__ __forceinline__ float reduce_scatter8(const float a[8], bool s1,
                                                 bool s2, bool s4) {
    float p0 = dpp_add<0xB1>(a[0]);   // pair sums (xor 1)
    float p1 = dpp_add<0xB1>(a[1]);
    float p2 = dpp_add<0xB1>(a[2]);
    float p3 = dpp_add<0xB1>(a[3]);
    float p4 = dpp_add<0xB1>(a[4]);
    float p5 = dpp_add<0xB1>(a[5]);
    float p6 = dpp_add<0xB1>(a[6]);
    float p7 = dpp_add<0xB1>(a[7]);
    float b0 = s1 ? p1 : p0;          // keep cols with bit0 == tau&1
    float b1 = s1 ? p3 : p2;
    float b2 = s1 ? p5 : p4;
    float b3 = s1 ? p7 : p6;
    float q0 = dpp_add<0x4E>(b0);     // quad sums (xor 2)
    float q1 = dpp_add<0x4E>(b1);
    float q2 = dpp_add<0x4E>(b2);
    float q3 = dpp_add<0x4E>(b3);
    float c0 = s2 ? q1 : q0;          // col tau&3
    float c1 = s2 ? q3 : q2;          // col 4 + (tau&3)
    float d0 = dpp_add<0x141>(c0);    // cross-quad (half mirror)
    float d1 = dpp_add<0x141>(c1);
    return s4 ? d1 : d0;              // col tau
}

// 256 blocks x 512 threads; block owns batches {2b, 2b+1}; 1 block/CU.
// Long-col dot (t<480): 8-lane group owns 8 consecutive cols of [rk1|k2];
//   lane ue owns u-slice [16ue,16ue+16). h1 batch-interleaved+padded in LDS;
//   one b128 read -> two (b0,b1) pairs -> packed FMA. reduce_scatter8 leaves
//   lane ue with the complete inner product of col 8cg+tau; ONE b32 write/batch.
// rk2 dot (t in [480,504)): 4 cols x full 32 u, no reduction needed.
// Both roles share ONE flat 128-float register array (wreg) — wave 7 spans
//   both roles; two arrays double live regs and spill (R5: 45 GB FETCH).
// Update: t<256 GRU1 unit (h_old in reg); t in [256,320) GRU2 lag-1 unit.
// Dot phase runs at EVERY iteration incl. drain i==TT (GRU2's last update
// needs k2·h1(TT-1) / rk2·h2(TT-2) computed there).
__global__ __launch_bounds__(512, 1)
void gru_stack_kernel(const float* __restrict__ x,   // [512,1024,1]
                      const float* __restrict__ k1,  // [1,384]
                      const float* __restrict__ rk1, // [128,384]
                      const float* __restrict__ b1,  // [2,384]
                      const float* __restrict__ k2,  // [128,96]
                      const float* __restrict__ rk2, // [32,96]
                      const float* __restrict__ b2,  // [2,96]
                      const float* __restrict__ wd,  // [32,1]
                      const float* __restrict__ bd,  // [1]
                      float* __restrict__ out)       // [512,1]
{
    // h1 interleaved: slice s (u=16s..16s+15): h1i[44*s + 2*j + b], pad 44.
    __shared__ __align__(16) float h1i[8 * 44];
    __shared__ __align__(16) float h2i[64];           // h2i[2*j + b]
    __shared__ __align__(16) float part1[2][480];     // complete inners: rk1|k2 cols
    __shared__ __align__(16) float part2[2][96];      // complete rk2 inners

    const int t  = threadIdx.x;
    const int b0 = blockIdx.x * 2;

    if (t < 8 * 44) h1i[t] = 0.f;
    if (t >= 448 && t < 512) h2i[t - 448] = 0.f;

    // ---------------- dot-role setup (single shared register array) ----------
    const int ue = t & 7, cg = t >> 3;
    const int tau = (ue & 4) ? (11 - ue) : ue;   // this lane's kept column
    const bool s1 = tau & 1, s2 = tau & 2, s4 = tau & 4;
    float wreg[128];
    if (t < 480) {
#pragma unroll
        for (int r = 0; r < 8; ++r) {
            const int c = 8 * cg + r;
#pragma unroll
            for (int j = 0; j < 16; ++j) {
                const int u = 16 * ue + j;
                wreg[r * 16 + j] = (c < 384) ? rk1[u * 384 + c]
                                             : k2[u * 96 + (c - 384)];
            }
        }
    } else if (t < 504) {
        const int c4 = 4 * (t - 480);
#pragma unroll
        for (int r = 0; r < 4; ++r)
#pragma unroll
            for (int u = 0; u < 32; ++u) wreg[r * 32 + u] = rk2[u * 96 + c4 + r];
    } else {
#pragma unroll
        for (int j = 0; j < 128; ++j) wreg[j] = 0.f;
    }

    // ---------------- update-role setup ----------------
    const int ju = t & 127, bu = t >> 7;               // t<256: GRU1 update
    float k1z = 0, k1r = 0, k1h = 0, bz = 0, br = 0, bhx = 0, bhr = 0, h_old = 0;
    if (t < 256) {
        k1z = k1[ju]; k1r = k1[128 + ju]; k1h = k1[256 + ju];
        bz  = b1[ju]       + b1[384 + ju];
        br  = b1[128 + ju] + b1[384 + 128 + ju];
        bhx = b1[256 + ju];
        bhr = b1[384 + 256 + ju];
    }
    const int tu = t - 256, j2 = tu & 31, bb2 = tu >> 5;  // [256,320): GRU2 update
    float bz2 = 0, br2 = 0, bh2x = 0, bh2r = 0, h2_old = 0;
    if (t >= 256 && t < 320) {
        bz2  = b2[j2]      + b2[96 + j2];
        br2  = b2[32 + j2] + b2[96 + 32 + j2];
        bh2x = b2[64 + j2];
        bh2r = b2[96 + 64 + j2];
    }

    __syncthreads();  // B0: h init visible

    for (int i = 0; i <= TT; ++i) {
        float xv = 0.f;
        if (t < 256 && i < TT) xv = x[(b0 + bu) * TT + i];

        // Dot phase: runs every iteration INCLUDING i==TT (pipeline drain).
        if (t < 480) {
            const float4* pb = (const float4*)&h1i[44 * ue];
            v2f acc[8];
#pragma unroll
            for (int r = 0; r < 8; ++r) acc[r] = (v2f){0.f, 0.f};
#pragma unroll
            for (int q = 0; q < 8; ++q) {          // 8 float4 = 16 u-pairs
                float4 hv = pb[q];
                v2f p0 = {hv.x, hv.y};             // (b0,b1) at u=16ue+2q
                v2f p1 = {hv.z, hv.w};             // u=16ue+2q+1
#pragma unroll
                for (int r = 0; r < 8; ++r) {
                    acc[r] += p0 * wreg[r * 16 + 2 * q];
                    acc[r] += p1 * wreg[r * 16 + 2 * q + 1];
                }
            }
            float a0[8], a1[8];
#pragma unroll
            for (int r = 0; r < 8; ++r) { a0[r] = acc[r].x; a1[r] = acc[r].y; }
            part1[0][8 * cg + tau] = reduce_scatter8(a0, s1, s2, s4);
            part1[1][8 * cg + tau] = reduce_scatter8(a1, s1, s2, s4);
        } else if (t < 504) {
            const int c4 = 4 * (t - 480);
            const float4* pb2 = (const float4*)h2i;
            v2f acc[4];
#pragma unroll
            for (int r = 0; r < 4; ++r) acc[r] = (v2f){0.f, 0.f};
#pragma unroll
            for (int q = 0; q < 16; ++q) {
                float4 hv = pb2[q];
                v2f p0 = {hv.x, hv.y};
                v2f p1 = {hv.z, hv.w};
#pragma unroll
                for (int r = 0; r < 4; ++r) {
                    acc[r] += p0 * wreg[r * 32 + 2 * q];
                    acc[r] += p1 * wreg[r * 32 + 2 * q + 1];
                }
            }
#pragma unroll
            for (int r = 0; r < 4; ++r) {
                part2[0][c4 + r] = acc[r].x;
                part2[1][c4 + r] = acc[r].y;
            }
        }
        __syncthreads();  // B1: inners visible

        if (t < 256 && i < TT) {
            // GRU1 unit update: z/r = relu, hh = tanh (reset_after)
            float iz = part1[bu][ju];
            float ir = part1[bu][128 + ju];
            float ih = part1[bu][256 + ju];
            float z  = fmaxf(fmaf(xv, k1z, bz) + iz, 0.f);
            float r  = fmaxf(fmaf(xv, k1r, br) + ir, 0.f);
            float hh = fast_tanh(fmaf(xv, k1h, bhx) + r * (ih + bhr));
            h_old = fmaf(z, h_old - hh, hh);
            h1i[44 * (ju >> 4) + 2 * (ju & 15) + bu] = h_old;
        } else if (t >= 256 && t < 320 && i >= 1) {
            // GRU2 unit update (one step behind): z/r = sigmoid, hh = relu
            float xz = part1[bb2][384 + j2];
            float xr = part1[bb2][384 + 32 + j2];
            float xh = part1[bb2][384 + 64 + j2];
            float iz = part2[bb2][j2];
            float ir = part2[bb2][32 + j2];
            float ih = part2[bb2][64 + j2];
            float z  = fast_sig(xz + iz + bz2);
            float r  = fast_sig(xr + ir + br2);
            float hh = fmaxf(xh + bh2x + r * (ih + bh2r), 0.f);
            h2_old = fmaf(z, h2_old - hh, hh);
            h2i[2 * j2 + bb2] = h2_old;
        }
        __syncthreads();  // B2: h updated
    }

    // ---------------- dense head ----------------
    if (t < 64) {
        const int b = t >> 5, j = t & 31;
        float p = h2i[2 * j + b] * wd[j];
#pragma unroll
        for (int m = 16; m >= 1; m >>= 1) p += __shfl_xor(p, m, 64);
        if (j == 0) out[b0 + b] = p + bd[0];
    }
}

extern "C" void kernel_launch(void* const* d_in, const int* in_sizes, int n_in,
                              void* d_out, int out_size, void* d_ws, size_t ws_size,
                              hipStream_t stream) {
    const float* x   = (const float*)d_in[0];
    const float* k1  = (const float*)d_in[1];
    const float* rk1 = (const float*)d_in[2];
    const float* b1  = (const float*)d_in[3];
    const float* k2  = (const float*)d_in[4];
    const float* rk2 = (const float*)d_in[5];
    const float* b2  = (const float*)d_in[6];
    const float* wd  = (const float*)d_in[7];
    const float* bd  = (const float*)d_in[8];
    float* out = (float*)d_out;

    dim3 grid(256), block(512);
    hipLaunchKernelGGL(gru_stack_kernel, grid, block, 0, stream,
                       x, k1, rk1, b1, k2, rk2, b2, wd, bd, out);
}

// Round 8
// 1288.468 us; speedup vs baseline: 28.9613x; 4.8738x over previous
//
#include <hip/hip_runtime.h>
#include <hip/hip_bf16.h>
#include <math.h>

typedef short  s8v __attribute__((ext_vector_type(8)));
typedef float  f4v __attribute__((ext_vector_type(4)));

#define TT 1024

__device__ __forceinline__ float fast_tanh(float v) {
    float e = __expf(2.f * v);      // v>>0: e=inf -> 1; v<<0: e=0 -> -1 (NaN-free)
    return 1.f - 2.f / (e + 1.f);
}
__device__ __forceinline__ float fast_sig(float v) {
    return 1.f / (1.f + __expf(-v));
}
__device__ __forceinline__ unsigned short f2bf(float f) {
    __hip_bfloat16 h = __float2bfloat16(f);
    return __builtin_bit_cast(unsigned short, h);
}
__device__ __forceinline__ float bf2f(unsigned short u) {
    __hip_bfloat16 h = __builtin_bit_cast(__hip_bfloat16, u);
    return __bfloat162float(h);
}
__device__ __forceinline__ f4v mfma16(s8v a, s8v b, f4v c) {
    return __builtin_amdgcn_mfma_f32_16x16x32_bf16(a, b, c, 0, 0, 0);
}

// 256 blocks x 512 threads (8 waves); block owns batches {2bi, 2bi+1}.
// TRANSPOSED MFMA GEMM: D = W^T(tile) · h^T via mfma_f32_16x16x32_bf16.
//   A = weight fragment (STATIC, register/AGPR-resident; loaded once, split
//       into bf16 hi+lo for fp32-grade accuracy: w·h ~= whi·hhi+whi·hlo+wlo·hhi).
//   B = h fragment: B[k][nn] = h[b=nn][32g+k] for nn<2, zeros otherwise
//       (zero lanes read a 16B zero pad; garbage cols never read back).
//   D (C-layout: col=lane&15=batch, row=4*(lane>>4)+reg = gate-col): lanes with
//       n<2 store one float4 = 4 complete inner products -> inner1[b][..].
// Waves 0-5: rk1's 24 M-tiles (4/wave), 4 K-tiles, 3 split terms = 48 MFMA.
// Waves 6-7: k2 (6 M-tiles, K=128) + rk2 (6 M-tiles, K=32) vs h2.
// Update: t<256 GRU1 unit (h_old in reg, writes bf16 hi/lo split of h1);
//         t in [256,320) GRU2 lag-1 unit (writes h2 split + h2f fp32).
// Same proven 2-barrier/step pipeline as R3; MFMA phase runs at i==TT (drain).
__global__ __launch_bounds__(512, 1)
void gru_stack_kernel(const float* __restrict__ x,   // [512,1024,1]
                      const float* __restrict__ k1,  // [1,384]
                      const float* __restrict__ rk1, // [128,384]
                      const float* __restrict__ b1,  // [2,384]
                      const float* __restrict__ k2,  // [128,96]
                      const float* __restrict__ rk2, // [32,96]
                      const float* __restrict__ b2,  // [2,96]
                      const float* __restrict__ wd,  // [32,1]
                      const float* __restrict__ bd,  // [1]
                      float* __restrict__ out)       // [512,1]
{
    __shared__ __align__(16) unsigned short h1hi[2][128];
    __shared__ __align__(16) unsigned short h1lo[2][128];
    __shared__ __align__(16) unsigned short h2hi[2][32];
    __shared__ __align__(16) unsigned short h2lo[2][32];
    __shared__ __align__(16) float h2f[2][32];
    __shared__ __align__(16) float inner1[2][480];   // rk1 (0..383) | k2 (384..479)
    __shared__ __align__(16) float inner2[2][96];    // rk2
    __shared__ __align__(16) float zpadf[4];         // 16B of zeros

    const int t    = threadIdx.x;
    const int b0   = blockIdx.x * 2;
    const int lane = t & 63;
    const int wv   = t >> 6;
    const int lg   = lane >> 4;    // k-subtile selector
    const int n    = lane & 15;    // batch column (valid: 0,1)
    const unsigned short* zpadu = (const unsigned short*)zpadf;

    if (t < 256) { ((unsigned short*)h1hi)[t] = 0; ((unsigned short*)h1lo)[t] = 0; }
    if (t < 64)  { ((unsigned short*)h2hi)[t] = 0; ((unsigned short*)h2lo)[t] = 0;
                   ((float*)h2f)[t] = 0.f; }
    if (t >= 508) zpadf[t - 508] = 0.f;

    // ---------------- update-role setup ----------------
    const int ju = t & 127, bu = t >> 7;               // t<256: GRU1 update
    float k1z = 0, k1r = 0, k1h = 0, bz = 0, br = 0, bhx = 0, bhr = 0, h_old = 0;
    if (t < 256) {
        k1z = k1[ju]; k1r = k1[128 + ju]; k1h = k1[256 + ju];
        bz  = b1[ju]       + b1[384 + ju];
        br  = b1[128 + ju] + b1[384 + 128 + ju];
        bhx = b1[256 + ju];
        bhr = b1[384 + 256 + ju];
    }
    const int tu = t - 256, j2 = tu & 31, bb2 = tu >> 5;  // [256,320): GRU2 update
    float bz2 = 0, br2 = 0, bh2x = 0, bh2r = 0, h2_old = 0;
    if (t >= 256 && t < 320) {
        bz2  = b2[j2]      + b2[96 + j2];
        br2  = b2[32 + j2] + b2[96 + 32 + j2];
        bh2x = b2[64 + j2];
        bh2r = b2[96 + 64 + j2];
    }

    if (wv < 6) {
        // ================= GRU1 GEMM waves (+ update roles) =================
        s8v awhi[4][4], awlo[4][4];    // [mt][g] static weight A-frags
#pragma unroll
        for (int mt = 0; mt < 4; ++mt) {
            const int c = 16 * (4 * wv + mt) + n;
#pragma unroll
            for (int g = 0; g < 4; ++g) {
                s8v hi8, lo8;
#pragma unroll
                for (int j = 0; j < 8; ++j) {
                    float w = rk1[(32 * g + 8 * lg + j) * 384 + c];
                    unsigned short wh = f2bf(w);
                    hi8[j] = (short)wh;
                    lo8[j] = (short)f2bf(w - bf2f(wh));
                }
                awhi[mt][g] = hi8; awlo[mt][g] = lo8;
            }
        }
        __syncthreads();  // B0

        for (int i = 0; i <= TT; ++i) {
            float xv = 0.f;
            if (t < 256 && i < TT) xv = x[(b0 + bu) * TT + i];

            // B-frags from h1 split (lanes n>=2 read the zero pad)
            s8v bh[4], bl[4];
#pragma unroll
            for (int g = 0; g < 4; ++g) {
                const unsigned short* sh = (n < 2) ? &h1hi[n][32 * g + 8 * lg] : zpadu;
                const unsigned short* sl = (n < 2) ? &h1lo[n][32 * g + 8 * lg] : zpadu;
                bh[g] = *(const s8v*)sh;
                bl[g] = *(const s8v*)sl;
            }
#pragma unroll
            for (int mt = 0; mt < 4; ++mt) {
                f4v acc = {0.f, 0.f, 0.f, 0.f};
#pragma unroll
                for (int g = 0; g < 4; ++g) {
                    acc = mfma16(awhi[mt][g], bh[g], acc);
                    acc = mfma16(awhi[mt][g], bl[g], acc);
                    acc = mfma16(awlo[mt][g], bh[g], acc);
                }
                if (n < 2)
                    *(f4v*)&inner1[n][16 * (4 * wv + mt) + 4 * lg] = acc;
            }
            __syncthreads();  // B1

            if (t < 256 && i < TT) {
                // GRU1 unit update: z/r = relu, hh = tanh (reset_after)
                float iz = inner1[bu][ju];
                float ir = inner1[bu][128 + ju];
                float ih = inner1[bu][256 + ju];
                float z  = fmaxf(fmaf(xv, k1z, bz) + iz, 0.f);
                float r  = fmaxf(fmaf(xv, k1r, br) + ir, 0.f);
                float hh = fast_tanh(fmaf(xv, k1h, bhx) + r * (ih + bhr));
                h_old = fmaf(z, h_old - hh, hh);
                unsigned short uhi = f2bf(h_old);
                float fhi = bf2f(uhi);
                unsigned short ulo = f2bf(h_old - fhi);
                h1hi[bu][ju] = uhi; h1lo[bu][ju] = ulo;
            } else if (t >= 256 && t < 320 && i >= 1) {
                // GRU2 unit update (one step behind): z/r = sigmoid, hh = relu
                float xz = inner1[bb2][384 + j2];
                float xr = inner1[bb2][384 + 32 + j2];
                float xh = inner1[bb2][384 + 64 + j2];
                float iz = inner2[bb2][j2];
                float ir = inner2[bb2][32 + j2];
                float ih = inner2[bb2][64 + j2];
                float z  = fast_sig(xz + iz + bz2);
                float r  = fast_sig(xr + ir + br2);
                float hh = fmaxf(xh + bh2x + r * (ih + bh2r), 0.f);
                h2_old = fmaf(z, h2_old - hh, hh);
                unsigned short uhi = f2bf(h2_old);
                float fhi = bf2f(uhi);
                unsigned short ulo = f2bf(h2_old - fhi);
                h2hi[bb2][j2] = uhi; h2lo[bb2][j2] = ulo;
                h2f[bb2][j2] = h2_old;
            }
            __syncthreads();  // B2
        }

        // ---------------- dense head (wave 4) ----------------
        if (t >= 256 && t < 320) {
            const int b = (t - 256) >> 5, j = (t - 256) & 31;
            float p = h2f[b][j] * wd[j];
#pragma unroll
            for (int m = 16; m >= 1; m >>= 1) p += __shfl_xor(p, m, 64);
            if (j == 0) out[b0 + b] = p + bd[0];
        }
    } else {
        // ================= GRU2 GEMM waves (k2 + rk2) =================
        const int wv2 = wv - 6;
        s8v a2hi[3][4], a2lo[3][4];   // k2 A-frags [mt][g]
        s8v arhi[3],    arlo[3];      // rk2 A-frags [mt] (K=32, one tile)
#pragma unroll
        for (int mt = 0; mt < 3; ++mt) {
            const int c = 16 * (3 * wv2 + mt) + n;
#pragma unroll
            for (int g = 0; g < 4; ++g) {
                s8v hi8, lo8;
#pragma unroll
                for (int j = 0; j < 8; ++j) {
                    float w = k2[(32 * g + 8 * lg + j) * 96 + c];
                    unsigned short wh = f2bf(w);
                    hi8[j] = (short)wh;
                    lo8[j] = (short)f2bf(w - bf2f(wh));
                }
                a2hi[mt][g] = hi8; a2lo[mt][g] = lo8;
            }
            s8v hi8, lo8;
#pragma unroll
            for (int j = 0; j < 8; ++j) {
                float w = rk2[(8 * lg + j) * 96 + c];
                unsigned short wh = f2bf(w);
                hi8[j] = (short)wh;
                lo8[j] = (short)f2bf(w - bf2f(wh));
            }
            arhi[mt] = hi8; arlo[mt] = lo8;
        }
        __syncthreads();  // B0

        for (int i = 0; i <= TT; ++i) {
            s8v bh[4], bl[4];
#pragma unroll
            for (int g = 0; g < 4; ++g) {
                const unsigned short* sh = (n < 2) ? &h1hi[n][32 * g + 8 * lg] : zpadu;
                const unsigned short* sl = (n < 2) ? &h1lo[n][32 * g + 8 * lg] : zpadu;
                bh[g] = *(const s8v*)sh;
                bl[g] = *(const s8v*)sl;
            }
            const unsigned short* rh = (n < 2) ? &h2hi[n][8 * lg] : zpadu;
            const unsigned short* rl = (n < 2) ? &h2lo[n][8 * lg] : zpadu;
            s8v rbh = *(const s8v*)rh;
            s8v rbl = *(const s8v*)rl;

#pragma unroll
            for (int mt = 0; mt < 3; ++mt) {
                f4v acc = {0.f, 0.f, 0.f, 0.f};
#pragma unroll
                for (int g = 0; g < 4; ++g) {
                    acc = mfma16(a2hi[mt][g], bh[g], acc);
                    acc = mfma16(a2hi[mt][g], bl[g], acc);
                    acc = mfma16(a2lo[mt][g], bh[g], acc);
                }
                if (n < 2)
                    *(f4v*)&inner1[n][384 + 16 * (3 * wv2 + mt) + 4 * lg] = acc;
            }
#pragma unroll
            for (int mt = 0; mt < 3; ++mt) {
                f4v acc = {0.f, 0.f, 0.f, 0.f};
                acc = mfma16(arhi[mt], rbh, acc);
                acc = mfma16(arhi[mt], rbl, acc);
                acc = mfma16(arlo[mt], rbh, acc);
                if (n < 2)
                    *(f4v*)&inner2[n][16 * (3 * wv2 + mt) + 4 * lg] = acc;
            }
            __syncthreads();  // B1
            __syncthreads();  // B2
        }
    }
}

extern "C" void kernel_launch(void* const* d_in, const int* in_sizes, int n_in,
                              void* d_out, int out_size, void* d_ws, size_t ws_size,
                              hipStream_t stream) {
    const float* x   = (const float*)d_in[0];
    const float* k1  = (const float*)d_in[1];
    const float* rk1 = (const float*)d_in[2];
    const float* b1  = (const float*)d_in[3];
    const float* k2  = (const float*)d_in[4];
    const float* rk2 = (const float*)d_in[5];
    const float* b2  = (const float*)d_in[6];
    const float* wd  = (const float*)d_in[7];
    const float* bd  = (const float*)d_in[8];
    float* out = (float*)d_out;

    dim3 grid(256), block(512);
    hipLaunchKernelGGL(gru_stack_kernel, grid, block, 0, stream,
                       x, k1, rk1, b1, k2, rk2, b2, wd, bd, out);
}